// Round 1
// baseline (656.156 us; speedup 1.0000x reference)
//
#include <hip/hip_runtime.h>
#include <hip/hip_bf16.h>

// TTT layer, one gradient step, fused.
// H=1024, D=256, tokens = B*T = 32768.
// out = S - lr*(2/N) * ((relu'(S W1+b1) .* ((relu(S W1+b1) W2 + b2 - T) W2^T)) W1^T)
// Stability-term gradient is identically zero at step 1 (s == s0).

#define Hdim 1024
#define Ddim 256
#define NTOK 32768
#define MT   32          // tokens per block

typedef __attribute__((ext_vector_type(8))) short bf16x8;
typedef __attribute__((ext_vector_type(4))) float f32x4;

static __device__ __forceinline__ unsigned short f2bf(float f) {
    unsigned u = __builtin_bit_cast(unsigned, f);
    u += 0x7FFFu + ((u >> 16) & 1u);          // RNE
    return (unsigned short)(u >> 16);
}

// Convert W1/W2 to bf16 in 4 layouts so every GEMM's B-operand is a
// contiguous 16B load per lane:
//  w1  [h][d]  (phase D: B[k=d][col=h] -> layout [col][k])
//  w1t [d][h]  (phase A: B[k=h][col=d])
//  w2  [d][h]  (phase C: B[k=h][col=d])
//  w2t [h][d]  (phase B: B[k=d][col=h])
__global__ void prep_weights(const float* __restrict__ W1, const float* __restrict__ W2,
                             unsigned short* __restrict__ w1, unsigned short* __restrict__ w1t,
                             unsigned short* __restrict__ w2, unsigned short* __restrict__ w2t) {
    int i = blockIdx.x * blockDim.x + threadIdx.x;
    if (i >= Hdim * Ddim) return;
    int h = i / Ddim, d = i - h * Ddim;
    unsigned short v1 = f2bf(W1[i]);             // W1[h][d]
    w1[i] = v1;
    w1t[d * Hdim + h] = v1;
    unsigned short v2 = f2bf(W2[d * Hdim + h]);  // W2[d][h]
    w2[d * Hdim + h] = v2;
    w2t[i] = v2;
}

__launch_bounds__(256, 2)
__global__ void ttt_fused(const float* __restrict__ state,
                          const float* __restrict__ target,
                          const float* __restrict__ b1,
                          const float* __restrict__ b2,
                          const float* __restrict__ step_size,
                          const unsigned short* __restrict__ w1,   // [h][d]
                          const unsigned short* __restrict__ w1t,  // [d][h]
                          const unsigned short* __restrict__ w2,   // [d][h]
                          const unsigned short* __restrict__ w2t,  // [h][d]
                          float* __restrict__ out) {
    // LDS: E tile [MT][Hdim] bf16 (64KB) + H/DH tile [MT][Ddim] bf16 (16KB)
    __shared__ unsigned char eld[MT * Hdim * 2];
    __shared__ unsigned char hld[MT * Ddim * 2];

    const int tid  = threadIdx.x;
    const int lane = tid & 63;
    const int wv   = tid >> 6;        // 0..3
    const int lr16 = lane & 15;
    const int lhi  = lane >> 4;       // 0..3
    const int kof  = lhi * 8;
    const int m0   = blockIdx.x * MT; // global token base

    const f32x4 z4 = {0.f, 0.f, 0.f, 0.f};

    // ---------------- Phase A: h = relu(S@W1 + b1) -> hld ----------------
    // wave wv owns cols [64*wv, 64*wv+64), all 32 rows (2 m-tiles)
    {
        f32x4 acc[2][4];
        #pragma unroll
        for (int mt = 0; mt < 2; ++mt)
            #pragma unroll
            for (int nt = 0; nt < 4; ++nt) acc[mt][nt] = z4;

        for (int kk = 0; kk < Hdim; kk += 32) {
            bf16x8 a[2];
            #pragma unroll
            for (int mt = 0; mt < 2; ++mt) {
                const float* sr = state + (size_t)(m0 + mt * 16 + lr16) * Hdim + kk + kof;
                float4 f0 = *(const float4*)sr;
                float4 f1 = *(const float4*)(sr + 4);
                bf16x8 av;
                av[0] = (short)f2bf(f0.x); av[1] = (short)f2bf(f0.y);
                av[2] = (short)f2bf(f0.z); av[3] = (short)f2bf(f0.w);
                av[4] = (short)f2bf(f1.x); av[5] = (short)f2bf(f1.y);
                av[6] = (short)f2bf(f1.z); av[7] = (short)f2bf(f1.w);
                a[mt] = av;
            }
            #pragma unroll
            for (int nt = 0; nt < 4; ++nt) {
                int col = wv * 64 + nt * 16 + lr16;
                bf16x8 b = *(const bf16x8*)(w1t + (size_t)col * Hdim + kk + kof);
                #pragma unroll
                for (int mt = 0; mt < 2; ++mt)
                    acc[mt][nt] = __builtin_amdgcn_mfma_f32_16x16x32_bf16(a[mt], b, acc[mt][nt], 0, 0, 0);
            }
        }
        float bias[4];
        #pragma unroll
        for (int nt = 0; nt < 4; ++nt) bias[nt] = b1[wv * 64 + nt * 16 + lr16];
        #pragma unroll
        for (int mt = 0; mt < 2; ++mt)
            #pragma unroll
            for (int nt = 0; nt < 4; ++nt) {
                int colg = wv * 64 + nt * 16 + lr16;
                #pragma unroll
                for (int i = 0; i < 4; ++i) {
                    int row = mt * 16 + lhi * 4 + i;
                    float hv = fmaxf(acc[mt][nt][i] + bias[nt], 0.f);
                    unsigned off = ((unsigned)(row * Ddim + colg) * 2u) ^ (unsigned)((row & 7) << 4);
                    *(unsigned short*)(hld + off) = f2bf(hv);
                }
            }
    }
    __syncthreads();

    // ---------------- Phase B: e = h@W2 + b2 - target -> eld ----------------
    // wave wv owns cols [256*wv, 256*wv+256), processed in 4 chunks of 64
    {
        for (int nc = 0; nc < 4; ++nc) {
            const int cb = wv * 256 + nc * 64;
            f32x4 acc[2][4];
            #pragma unroll
            for (int mt = 0; mt < 2; ++mt)
                #pragma unroll
                for (int nt = 0; nt < 4; ++nt) acc[mt][nt] = z4;

            for (int kk = 0; kk < Ddim; kk += 32) {
                bf16x8 a[2];
                #pragma unroll
                for (int mt = 0; mt < 2; ++mt) {
                    int row = mt * 16 + lr16;
                    unsigned off = ((unsigned)(row * Ddim + kk + kof) * 2u) ^ (unsigned)((row & 7) << 4);
                    a[mt] = *(const bf16x8*)(hld + off);
                }
                #pragma unroll
                for (int nt = 0; nt < 4; ++nt) {
                    int col = cb + nt * 16 + lr16;
                    bf16x8 b = *(const bf16x8*)(w2t + (size_t)col * Ddim + kk + kof);
                    #pragma unroll
                    for (int mt = 0; mt < 2; ++mt)
                        acc[mt][nt] = __builtin_amdgcn_mfma_f32_16x16x32_bf16(a[mt], b, acc[mt][nt], 0, 0, 0);
                }
            }
            float bias[4];
            #pragma unroll
            for (int nt = 0; nt < 4; ++nt) bias[nt] = b2[cb + nt * 16 + lr16];
            #pragma unroll
            for (int nt = 0; nt < 4; ++nt) {
                int colg = cb + nt * 16 + lr16;
                #pragma unroll
                for (int mt = 0; mt < 2; ++mt)
                    #pragma unroll
                    for (int i = 0; i < 4; ++i) {
                        int row = mt * 16 + lhi * 4 + i;
                        float e = acc[mt][nt][i] + bias[nt]
                                - target[(size_t)(m0 + row) * Hdim + colg];
                        unsigned off = ((unsigned)(row * Hdim + colg) * 2u) ^ (unsigned)((row & 7) << 4);
                        *(unsigned short*)(eld + off) = f2bf(e);
                    }
            }
        }
    }
    __syncthreads();

    // ---------------- Phase C: dh = (e@W2^T) .* mask -> hld (in place) ----------------
    // wave wv owns cols [64*wv, 64*wv+64) of D
    {
        f32x4 acc[2][4];
        #pragma unroll
        for (int mt = 0; mt < 2; ++mt)
            #pragma unroll
            for (int nt = 0; nt < 4; ++nt) acc[mt][nt] = z4;

        for (int kk = 0; kk < Hdim; kk += 32) {
            bf16x8 a[2];
            #pragma unroll
            for (int mt = 0; mt < 2; ++mt) {
                int row = mt * 16 + lr16;
                unsigned off = ((unsigned)(row * Hdim + kk + kof) * 2u) ^ (unsigned)((row & 7) << 4);
                a[mt] = *(const bf16x8*)(eld + off);
            }
            #pragma unroll
            for (int nt = 0; nt < 4; ++nt) {
                int col = wv * 64 + nt * 16 + lr16;  // d index
                bf16x8 b = *(const bf16x8*)(w2 + (size_t)col * Hdim + kk + kof);
                #pragma unroll
                for (int mt = 0; mt < 2; ++mt)
                    acc[mt][nt] = __builtin_amdgcn_mfma_f32_16x16x32_bf16(a[mt], b, acc[mt][nt], 0, 0, 0);
            }
        }
        // mask read then in-place overwrite: each (row,col) owned by exactly one lane
        #pragma unroll
        for (int mt = 0; mt < 2; ++mt)
            #pragma unroll
            for (int nt = 0; nt < 4; ++nt) {
                int colg = wv * 64 + nt * 16 + lr16;
                #pragma unroll
                for (int i = 0; i < 4; ++i) {
                    int row = mt * 16 + lhi * 4 + i;
                    unsigned off = ((unsigned)(row * Ddim + colg) * 2u) ^ (unsigned)((row & 7) << 4);
                    unsigned short hbits = *(const unsigned short*)(hld + off);
                    float dh = (hbits != 0) ? acc[mt][nt][i] : 0.f;  // h>0 (h>=0 always)
                    *(unsigned short*)(hld + off) = f2bf(dh);
                }
            }
    }
    __syncthreads();

    // ---------------- Phase D: out = S - c * (dh@W1^T) ----------------
    {
        const float cc = step_size[0] * (2.0f / (float)((long long)NTOK * Hdim));
        for (int nc = 0; nc < 4; ++nc) {
            const int cb = wv * 256 + nc * 64;
            f32x4 acc[2][4];
            #pragma unroll
            for (int mt = 0; mt < 2; ++mt)
                #pragma unroll
                for (int nt = 0; nt < 4; ++nt) acc[mt][nt] = z4;

            for (int kk = 0; kk < Ddim; kk += 32) {
                bf16x8 a[2];
                #pragma unroll
                for (int mt = 0; mt < 2; ++mt) {
                    int row = mt * 16 + lr16;
                    unsigned off = ((unsigned)(row * Ddim + kk + kof) * 2u) ^ (unsigned)((row & 7) << 4);
                    a[mt] = *(const bf16x8*)(hld + off);
                }
                #pragma unroll
                for (int nt = 0; nt < 4; ++nt) {
                    int col = cb + nt * 16 + lr16;   // h index
                    bf16x8 b = *(const bf16x8*)(w1 + (size_t)col * Ddim + kk + kof);
                    #pragma unroll
                    for (int mt = 0; mt < 2; ++mt)
                        acc[mt][nt] = __builtin_amdgcn_mfma_f32_16x16x32_bf16(a[mt], b, acc[mt][nt], 0, 0, 0);
                }
            }
            #pragma unroll
            for (int nt = 0; nt < 4; ++nt) {
                int colg = cb + nt * 16 + lr16;
                #pragma unroll
                for (int mt = 0; mt < 2; ++mt)
                    #pragma unroll
                    for (int i = 0; i < 4; ++i) {
                        int row = mt * 16 + lhi * 4 + i;
                        size_t gi = (size_t)(m0 + row) * Hdim + colg;
                        out[gi] = state[gi] - cc * acc[mt][nt][i];
                    }
            }
        }
    }
}

extern "C" void kernel_launch(void* const* d_in, const int* in_sizes, int n_in,
                              void* d_out, int out_size, void* d_ws, size_t ws_size,
                              hipStream_t stream) {
    const float* state     = (const float*)d_in[0];
    const float* target    = (const float*)d_in[1];
    const float* W1        = (const float*)d_in[2];
    const float* b1        = (const float*)d_in[3];
    const float* W2        = (const float*)d_in[4];
    const float* b2        = (const float*)d_in[5];
    const float* step_size = (const float*)d_in[6];
    float* out = (float*)d_out;

    // workspace: 4 bf16 weight layouts, 512KB each = 2MB total
    unsigned short* w1  = (unsigned short*)d_ws;
    unsigned short* w1t = w1  + Hdim * Ddim;
    unsigned short* w2  = w1t + Hdim * Ddim;
    unsigned short* w2t = w2  + Hdim * Ddim;

    hipLaunchKernelGGL(prep_weights, dim3((Hdim * Ddim + 255) / 256), dim3(256), 0, stream,
                       W1, W2, w1, w1t, w2, w2t);
    hipLaunchKernelGGL(ttt_fused, dim3(NTOK / MT), dim3(256), 0, stream,
                       state, target, b1, b2, step_size, w1, w1t, w2, w2t, out);
}